// Round 4
// baseline (430.299 us; speedup 1.0000x reference)
//
#include <hip/hip_runtime.h>
#include <hip/hip_bf16.h>
#include <string.h>

#define BATCH 8
#define DM 1024
#define NS 64
#define SL 2048
#define NC 32
#define TC 64   // SL/NC

typedef float v2f __attribute__((ext_vector_type(2)));

// ws layout (floats):
//  BuT: [B][SL][NS]  f32  off 0         (4MB)
//  CuT: [B][SL][NS]  f32  off 1048576   (4MB)
//  W  : [B][SL][NS]  f32  off 2097152   (4MB)   Cu * a^((l%TC)+1)
//  E  : [B][NC][DM][NS] bf16 at float-off 3145728 (32MB; becomes HS in place)

static __device__ inline v2f bfpair_to_v2f(unsigned int p) {
    unsigned int lo = p << 16, hi = p & 0xffff0000u;
    v2f r;
    r.x = __uint_as_float(lo);
    r.y = __uint_as_float(hi);
    return r;
}

// ---------------- kernel 1: Bu/Cu projections (transposed) + W ----------------
// grid (SL/32, BATCH), block 256. Wave-uniform g = t>>6 covers 8 l's per thread.
__global__ __launch_bounds__(256) void k_bucu(const float* __restrict__ u,
                                              const float* __restrict__ A,
                                              const float* __restrict__ B,
                                              const float* __restrict__ C,
                                              float* __restrict__ BuT,
                                              float* __restrict__ CuT,
                                              float* __restrict__ W)
{
    __shared__ float su[32][32];          // [d-sub][l-tile] 4KB
    const int b  = blockIdx.y;
    const int l0 = blockIdx.x * 32;
    const int t  = threadIdx.x;
    const int n  = t & 63;
    const int g  = t >> 6;                // wave-uniform (wave64)

    v2f accB[4], accC[4];
#pragma unroll
    for (int i = 0; i < 4; i++) { accB[i] = (v2f){0.f, 0.f}; accC[i] = (v2f){0.f, 0.f}; }

#pragma unroll 1
    for (int d0 = 0; d0 < DM; d0 += 32) {
        __syncthreads();
        {   // stage u[b][d0+r][l0 + f..f+4): 1024 floats, 1 float4/thread
            int r = t >> 3, f = (t & 7) * 4;
            float4 v = *(const float4*)&u[((size_t)b * DM + d0 + r) * SL + l0 + f];
            su[r][f] = v.x; su[r][f + 1] = v.y; su[r][f + 2] = v.z; su[r][f + 3] = v.w;
        }
        __syncthreads();
#pragma unroll 4
        for (int dd = 0; dd < 32; dd++) {
            float bv = B[(size_t)(d0 + dd) * NS + n];   // coalesced, L2-resident
            float cv = C[(size_t)(d0 + dd) * NS + n];
            const v2f* urow = (const v2f*)&su[dd][g * 8]; // wave-uniform broadcast
            v2f bv2 = { bv, bv }, cv2 = { cv, cv };
#pragma unroll
            for (int i = 0; i < 4; i++) {
                v2f uv = urow[i];
                accB[i] = __builtin_elementwise_fma(bv2, uv, accB[i]);
                accC[i] = __builtin_elementwise_fma(cv2, uv, accC[i]);
            }
        }
    }
    const float an = A[n * NS + n];
#pragma unroll
    for (int i = 0; i < 4; i++) {
        int l = l0 + g * 8 + i * 2;
        size_t o0 = ((size_t)b * SL + l) * NS + n;
        size_t o1 = o0 + NS;
        BuT[o0] = accB[i].x;  BuT[o1] = accB[i].y;
        CuT[o0] = accC[i].x;  CuT[o1] = accC[i].y;
        W[o0] = accC[i].x * __powf(an, (float)((l & (TC - 1)) + 1));
        W[o1] = accC[i].y * __powf(an, (float)(((l + 1) & (TC - 1)) + 1));
    }
}

// ---------------- kernel 2: per-chunk local scan (zero init) ----------------
// grid (DM/512, NC, BATCH), block 256. Thread owns d and d+256; n packed in v2f pairs.
__global__ __launch_bounds__(256) void k_scan(const float* __restrict__ u,
                                              const float* __restrict__ A,
                                              const float* __restrict__ BuT,
                                              const float* __restrict__ CuT,
                                              __hip_bfloat16* __restrict__ E,
                                              float* __restrict__ y)
{
    const int c  = blockIdx.y;
    const int b  = blockIdx.z;
    const int t  = threadIdx.x;
    const int dA = blockIdx.x * 512 + t;
    const int dB = dA + 256;
    const int l0 = c * TC;

    float as[64];
#pragma unroll
    for (int j = 0; j < 64; j++) as[j] = A[j * NS + j];   // uniform -> SGPRs

    v2f hA[32], hB[32];
#pragma unroll
    for (int j = 0; j < 32; j++) { hA[j] = (v2f){0.f, 0.f}; hB[j] = (v2f){0.f, 0.f}; }

    const float* uAp = u + ((size_t)b * DM + dA) * SL + l0;
    const float* uBp = u + ((size_t)b * DM + dB) * SL + l0;
    float*       yAp = y + ((size_t)b * DM + dA) * SL + l0;
    float*       yBp = y + ((size_t)b * DM + dB) * SL + l0;
    const float* coefB = BuT + (size_t)(b * SL + l0) * NS;
    const float* coefC = CuT + (size_t)(b * SL + l0) * NS;

    float4 uA4 = *(const float4*)uAp;
    float4 uB4 = *(const float4*)uBp;

#pragma unroll 1
    for (int lq = 0; lq < TC / 4; lq++) {
        float4 nA, nB;
        if (lq + 1 < TC / 4) {           // software prefetch next 4 u values
            nA = *(const float4*)(uAp + (lq + 1) * 4);
            nB = *(const float4*)(uBp + (lq + 1) * 4);
        }
        float uaA[4] = { uA4.x, uA4.y, uA4.z, uA4.w };
        float uaB[4] = { uB4.x, uB4.y, uB4.z, uB4.w };
        float yrA[4], yrB[4];
#pragma unroll
        for (int i = 0; i < 4; i++) {
            const int l = lq * 4 + i;
            const float4* bu4p = (const float4*)(coefB + (size_t)l * NS);  // uniform addr
            const float4* cu4p = (const float4*)(coefC + (size_t)l * NS);
            v2f sA = { uaA[i], uaA[i] };
            v2f sB = { uaB[i], uaB[i] };
            v2f yA0 = {0.f,0.f}, yA1 = {0.f,0.f}, yB0 = {0.f,0.f}, yB1 = {0.f,0.f};
#pragma unroll
            for (int k = 0; k < 16; k++) {
                float4 bu = bu4p[k];
                float4 cu = cu4p[k];
                v2f bu_lo = { bu.x, bu.y }, bu_hi = { bu.z, bu.w };
                v2f cu_lo = { cu.x, cu.y }, cu_hi = { cu.z, cu.w };
                v2f a_lo  = { as[4*k],   as[4*k+1] };
                v2f a_hi  = { as[4*k+2], as[4*k+3] };
                int p = 2 * k, q = 2 * k + 1;
                hA[p] = __builtin_elementwise_fma(a_lo, hA[p], bu_lo * sA);
                yA0   = __builtin_elementwise_fma(cu_lo, hA[p], yA0);
                hA[q] = __builtin_elementwise_fma(a_hi, hA[q], bu_hi * sA);
                yA1   = __builtin_elementwise_fma(cu_hi, hA[q], yA1);
                hB[p] = __builtin_elementwise_fma(a_lo, hB[p], bu_lo * sB);
                yB0   = __builtin_elementwise_fma(cu_lo, hB[p], yB0);
                hB[q] = __builtin_elementwise_fma(a_hi, hB[q], bu_hi * sB);
                yB1   = __builtin_elementwise_fma(cu_hi, hB[q], yB1);
            }
            v2f yA2 = yA0 + yA1, yB2 = yB0 + yB1;
            yrA[i] = yA2.x + yA2.y;
            yrB[i] = yB2.x + yB2.y;
        }
        float4 oA = { yrA[0], yrA[1], yrA[2], yrA[3] };
        float4 oB = { yrB[0], yrB[1], yrB[2], yrB[3] };
        *(float4*)(yAp + lq * 4) = oA;
        *(float4*)(yBp + lq * 4) = oB;
        uA4 = nA; uB4 = nB;
    }

    // E[b][c][d][n] bf16, packed pairs
    __hip_bfloat162* eA = (__hip_bfloat162*)(E + (((size_t)(b * NC + c) * DM) + dA) * NS);
    __hip_bfloat162* eB = (__hip_bfloat162*)(E + (((size_t)(b * NC + c) * DM) + dB) * NS);
#pragma unroll
    for (int k = 0; k < 32; k++) {
        __hip_bfloat162 ta, tb;
        ta.x = __float2bfloat16(hA[k].x); ta.y = __float2bfloat16(hA[k].y);
        tb.x = __float2bfloat16(hB[k].x); tb.y = __float2bfloat16(hB[k].y);
        eA[k] = ta;
        eB[k] = tb;
    }
}

// ---------------- kernel 3: prefix over chunks (E -> HS, in place) ----------------
// thread = (b, d, 16-n group). grid 128 blocks x 256.
__global__ __launch_bounds__(256) void k_prefix(const float* __restrict__ A,
                                                __hip_bfloat16* __restrict__ E)
{
    int g  = blockIdx.x * 256 + threadIdx.x;     // 0 .. 32767
    int ng = g & 3;
    int d  = (g >> 2) & (DM - 1);
    int b  = g >> 12;
    int n0 = ng * 16;

    v2f aT[8];
#pragma unroll
    for (int j = 0; j < 8; j++) {
        float a0 = A[(n0 + 2 * j) * NS + (n0 + 2 * j)];
        float a1 = A[(n0 + 2 * j + 1) * NS + (n0 + 2 * j + 1)];
        aT[j].x = __powf(a0, (float)TC);
        aT[j].y = __powf(a1, (float)TC);
    }

    v2f hs[8];
#pragma unroll
    for (int j = 0; j < 8; j++) hs[j] = (v2f){0.f, 0.f};

#pragma unroll 1
    for (int c = 0; c < NC; c++) {
        unsigned int* p = (unsigned int*)(E + (((size_t)b * NC + c) * DM + d) * NS + n0);
        uint4 e0 = *(uint4*)p;
        uint4 e1 = *(uint4*)(p + 4);
        unsigned int ew[8] = { e0.x, e0.y, e0.z, e0.w, e1.x, e1.y, e1.z, e1.w };
        // write state at START of chunk c, then fold chunk c's end-state in
        unsigned int sw[8];
#pragma unroll
        for (int j = 0; j < 8; j++) {
            __hip_bfloat162 tp;
            tp.x = __float2bfloat16(hs[j].x);
            tp.y = __float2bfloat16(hs[j].y);
            unsigned int w;
            memcpy(&w, &tp, 4);
            sw[j] = w;
        }
        uint4 s0 = { sw[0], sw[1], sw[2], sw[3] };
        uint4 s1 = { sw[4], sw[5], sw[6], sw[7] };
        *(uint4*)p = s0;
        *(uint4*)(p + 4) = s1;
#pragma unroll
        for (int j = 0; j < 8; j++)
            hs[j] = __builtin_elementwise_fma(aT[j], hs[j], bfpair_to_v2f(ew[j]));
    }
}

// ---------------- kernel 4: cross-chunk correction ----------------
// grid (DM/512, NC-1, BATCH), block 256. Thread owns d and d+256.
__global__ __launch_bounds__(256) void k_corr(const __hip_bfloat16* __restrict__ HS,
                                              const float* __restrict__ W,
                                              float* __restrict__ y)
{
    const int c  = blockIdx.y + 1;               // chunk 0 has zero start state
    const int b  = blockIdx.z;
    const int t  = threadIdx.x;
    const int dA = blockIdx.x * 512 + t;
    const int dB = dA + 256;
    const int l0 = c * TC;

    v2f hsA[32], hsB[32];
    {
        const unsigned int* pA = (const unsigned int*)(HS + (((size_t)b * NC + c) * DM + dA) * NS);
        const unsigned int* pB = (const unsigned int*)(HS + (((size_t)b * NC + c) * DM + dB) * NS);
#pragma unroll
        for (int q = 0; q < 8; q++) {
            uint4 va = *(const uint4*)(pA + q * 4);
            uint4 vb = *(const uint4*)(pB + q * 4);
            hsA[q * 4 + 0] = bfpair_to_v2f(va.x);
            hsA[q * 4 + 1] = bfpair_to_v2f(va.y);
            hsA[q * 4 + 2] = bfpair_to_v2f(va.z);
            hsA[q * 4 + 3] = bfpair_to_v2f(va.w);
            hsB[q * 4 + 0] = bfpair_to_v2f(vb.x);
            hsB[q * 4 + 1] = bfpair_to_v2f(vb.y);
            hsB[q * 4 + 2] = bfpair_to_v2f(vb.z);
            hsB[q * 4 + 3] = bfpair_to_v2f(vb.w);
        }
    }

    float* yAp = y + ((size_t)b * DM + dA) * SL + l0;
    float* yBp = y + ((size_t)b * DM + dB) * SL + l0;
    const float* wBase = W + (size_t)(b * SL + l0) * NS;

#pragma unroll 1
    for (int lq = 0; lq < TC / 4; lq++) {
        float4 yA4 = *(float4*)(yAp + lq * 4);
        float4 yB4 = *(float4*)(yBp + lq * 4);
        float accA[4], accB[4];
#pragma unroll
        for (int i = 0; i < 4; i++) {
            const float4* w4p = (const float4*)(wBase + (size_t)(lq * 4 + i) * NS); // uniform
            v2f yA0 = {0.f,0.f}, yA1 = {0.f,0.f}, yB0 = {0.f,0.f}, yB1 = {0.f,0.f};
#pragma unroll
            for (int k = 0; k < 16; k++) {
                float4 w = w4p[k];
                v2f w_lo = { w.x, w.y }, w_hi = { w.z, w.w };
                int p = 2 * k, q = 2 * k + 1;
                yA0 = __builtin_elementwise_fma(w_lo, hsA[p], yA0);
                yA1 = __builtin_elementwise_fma(w_hi, hsA[q], yA1);
                yB0 = __builtin_elementwise_fma(w_lo, hsB[p], yB0);
                yB1 = __builtin_elementwise_fma(w_hi, hsB[q], yB1);
            }
            v2f yA2 = yA0 + yA1, yB2 = yB0 + yB1;
            accA[i] = yA2.x + yA2.y;
            accB[i] = yB2.x + yB2.y;
        }
        yA4.x += accA[0]; yA4.y += accA[1]; yA4.z += accA[2]; yA4.w += accA[3];
        yB4.x += accB[0]; yB4.y += accB[1]; yB4.z += accB[2]; yB4.w += accB[3];
        *(float4*)(yAp + lq * 4) = yA4;
        *(float4*)(yBp + lq * 4) = yB4;
    }
}

extern "C" void kernel_launch(void* const* d_in, const int* in_sizes, int n_in,
                              void* d_out, int out_size, void* d_ws, size_t ws_size,
                              hipStream_t stream) {
    const float* u = (const float*)d_in[1];
    const float* A = (const float*)d_in[2];
    const float* B = (const float*)d_in[3];
    const float* C = (const float*)d_in[4];
    float* y = (float*)d_out;

    float* ws  = (float*)d_ws;
    float* BuT = ws;
    float* CuT = ws + 1048576;
    float* W   = ws + 2097152;
    __hip_bfloat16* E = (__hip_bfloat16*)(ws + 3145728);

    k_bucu<<<dim3(SL / 32, BATCH), 256, 0, stream>>>(u, A, B, C, BuT, CuT, W);
    k_scan<<<dim3(DM / 512, NC, BATCH), 256, 0, stream>>>(u, A, BuT, CuT, E, y);
    k_prefix<<<dim3(BATCH * DM * 4 / 256), 256, 0, stream>>>(A, E);
    k_corr<<<dim3(DM / 512, NC - 1, BATCH), 256, 0, stream>>>(E, W, y);
}